// Round 1
// baseline (20.759 us; speedup 1.0000x reference)
//
#include <hip/hip_runtime.h>

// CenterLoss: mean_i clip(||x_i - c_{labels[i]}||^2, 1e-12, 1e12)
// N=8192, D=128, M=32000. Only the selected rows of `center` are needed —
// no [N,M] distance matrix, no GEMM.

#define N_ROWS 8192
#define DIM    128

// One 64-lane wave per row; lane l covers elements [2l, 2l+1] (float2).
__global__ void centerloss_partial(const float* __restrict__ x,
                                   const float* __restrict__ c,
                                   const int*   __restrict__ labels,
                                   float* __restrict__ partial) {
    const int lane   = threadIdx.x & 63;
    const int wid    = threadIdx.x >> 6;            // wave id in block
    const int gwave  = (blockIdx.x * blockDim.x + threadIdx.x) >> 6;
    const int nwaves = (gridDim.x * blockDim.x) >> 6;

    float acc = 0.0f;   // per-lane0 accumulator of clipped row distances

    for (int row = gwave; row < N_ROWS; row += nwaves) {
        const int lbl = labels[row];
        const float2 xv = *reinterpret_cast<const float2*>(x + (size_t)row * DIM + lane * 2);
        const float2 cv = *reinterpret_cast<const float2*>(c + (size_t)lbl * DIM + lane * 2);
        const float d0 = xv.x - cv.x;
        const float d1 = xv.y - cv.y;
        float s = d0 * d0 + d1 * d1;
        // 64-lane butterfly/down reduce
        #pragma unroll
        for (int off = 32; off > 0; off >>= 1)
            s += __shfl_down(s, off, 64);
        if (lane == 0) {
            s = fminf(fmaxf(s, 1e-12f), 1e12f);
            acc += s;
        }
    }

    __shared__ float lds[16];   // up to 16 waves/block (block<=1024)
    if (lane == 0) lds[wid] = acc;
    __syncthreads();
    if (threadIdx.x == 0) {
        float s = 0.0f;
        const int nw = blockDim.x >> 6;
        for (int w = 0; w < nw; ++w) s += lds[w];
        partial[blockIdx.x] = s;
    }
}

__global__ void centerloss_final(const float* __restrict__ partial,
                                 int nparts,
                                 float* __restrict__ out) {
    float s = 0.0f;
    for (int i = threadIdx.x; i < nparts; i += 64) s += partial[i];
    #pragma unroll
    for (int off = 32; off > 0; off >>= 1)
        s += __shfl_down(s, off, 64);
    if (threadIdx.x == 0) out[0] = s * (1.0f / (float)N_ROWS);
}

extern "C" void kernel_launch(void* const* d_in, const int* in_sizes, int n_in,
                              void* d_out, int out_size, void* d_ws, size_t ws_size,
                              hipStream_t stream) {
    const float* x      = (const float*)d_in[0];   // [8192, 128] fp32
    const float* center = (const float*)d_in[1];   // [32000, 128] fp32
    const int*   labels = (const int*)d_in[2];     // [8192] int
    float* out = (float*)d_out;
    float* partial = (float*)d_ws;                 // 64 floats of scratch

    const int BLOCKS = 64;     // 64 blocks * 4 waves = 256 waves; 32 rows/wave
    const int THREADS = 256;
    centerloss_partial<<<BLOCKS, THREADS, 0, stream>>>(x, center, labels, partial);
    centerloss_final<<<1, 64, 0, stream>>>(partial, BLOCKS, out);
}

// Round 2
// 12.266 us; speedup vs baseline: 1.6924x; 1.6924x over previous
//
#include <hip/hip_runtime.h>

// CenterLoss: mean_i clip(||x_i - c_{labels[i]}||^2, 1e-12, 1e12)
// N=8192, D=128, M=32000. Only the selected rows of `center` are needed.
// One wave per row, 8192 waves total -> all latency hidden by TLP.

#define N_ROWS 8192
#define DIM    128
#define BLOCKS 2048          // 2048 blocks * 4 waves = 8192 waves = 1 row/wave
#define THREADS 256

__global__ __launch_bounds__(THREADS) void centerloss_partial(
        const float* __restrict__ x,
        const float* __restrict__ c,
        const int*   __restrict__ labels,
        float* __restrict__ partial) {
    const int lane = threadIdx.x & 63;
    const int wid  = threadIdx.x >> 6;                   // wave in block (0..3)
    const int row  = blockIdx.x * 4 + wid;               // one row per wave

    const int lbl = labels[row];
    const float2 xv = *reinterpret_cast<const float2*>(x + (size_t)row * DIM + lane * 2);
    const float2 cv = *reinterpret_cast<const float2*>(c + (size_t)lbl * DIM + lane * 2);
    const float d0 = xv.x - cv.x;
    const float d1 = xv.y - cv.y;
    float s = d0 * d0 + d1 * d1;

    #pragma unroll
    for (int off = 32; off > 0; off >>= 1)
        s += __shfl_down(s, off, 64);

    __shared__ float lds[4];
    if (lane == 0)
        lds[wid] = fminf(fmaxf(s, 1e-12f), 1e12f);
    __syncthreads();
    if (threadIdx.x == 0)
        partial[blockIdx.x] = lds[0] + lds[1] + lds[2] + lds[3];
}

__global__ __launch_bounds__(256) void centerloss_final(
        const float* __restrict__ partial,
        float* __restrict__ out) {
    const int lane = threadIdx.x & 63;
    const int wid  = threadIdx.x >> 6;
    float s = 0.0f;
    for (int i = threadIdx.x; i < BLOCKS; i += 256)      // 8 iters, coalesced
        s += partial[i];
    #pragma unroll
    for (int off = 32; off > 0; off >>= 1)
        s += __shfl_down(s, off, 64);
    __shared__ float lds[4];
    if (lane == 0) lds[wid] = s;
    __syncthreads();
    if (threadIdx.x == 0)
        out[0] = (lds[0] + lds[1] + lds[2] + lds[3]) * (1.0f / (float)N_ROWS);
}

extern "C" void kernel_launch(void* const* d_in, const int* in_sizes, int n_in,
                              void* d_out, int out_size, void* d_ws, size_t ws_size,
                              hipStream_t stream) {
    const float* x      = (const float*)d_in[0];   // [8192, 128] fp32
    const float* center = (const float*)d_in[1];   // [32000, 128] fp32
    const int*   labels = (const int*)d_in[2];     // [8192] int
    float* out = (float*)d_out;
    float* partial = (float*)d_ws;                 // 2048 floats of scratch

    centerloss_partial<<<BLOCKS, THREADS, 0, stream>>>(x, center, labels, partial);
    centerloss_final<<<1, 256, 0, stream>>>(partial, out);
}